// Round 8
// baseline (232.523 us; speedup 1.0000x reference)
//
#include <hip/hip_runtime.h>
#include <stdint.h>

// ---------------------------------------------------------------------------
// out = softmax((x Wq^T + bq)(x Wk^T + bk)^T / 8) (x Wk^T + bk) Wo^T + bo
// (v = k per the reference's faithful bug)
// B=8 S=1024 E=768 NH=12 D=64.  All GEMMs bf16-MFMA with fp32 accumulate.
// ---------------------------------------------------------------------------

using short8   = __attribute__((ext_vector_type(8))) short;
using uint4v   = __attribute__((ext_vector_type(4))) unsigned;
using float4v  = __attribute__((ext_vector_type(4))) float;
using float16v = __attribute__((ext_vector_type(16))) float;

struct __align__(8) U2 { unsigned x, y; };

__device__ __forceinline__ void async16(void* lds, const void* g) {
  __builtin_amdgcn_global_load_lds(
      (const __attribute__((address_space(1))) void*)g,
      (__attribute__((address_space(3))) void*)lds, 16, 0, 0);
}

// explicit vm-wait: compiler does NOT track global_load_lds -> ds_read deps
#define VM_WAIT(n) asm volatile("s_waitcnt vmcnt(" #n ")" ::: "memory")
#define LGKM_WAIT  asm volatile("s_waitcnt lgkmcnt(0)" ::: "memory")
// bare workgroup barrier WITHOUT the vmcnt(0) drain __syncthreads forces:
// in-flight prefetch DMAs cross it untouched.
#define BARRIER    asm volatile("s_barrier" ::: "memory")

// fp32 -> bf16 bits, round-to-nearest-even
__device__ __forceinline__ unsigned bf16b(float f) {
  union { float f; unsigned u; } v; v.f = f;
  unsigned r = v.u + 0x7FFFu + ((v.u >> 16) & 1u);
  return r >> 16;
}
// RNE adjust only (bf16 = high 16 bits of result): 2 VALU
__device__ __forceinline__ unsigned rne_adj(float f) {
  union { float f; unsigned u; } v; v.f = f;
  return v.u + 0x7FFFu + ((v.u >> 16) & 1u);
}
// pack hi16(a):hi16(b) -> one v_perm_b32
__device__ __forceinline__ unsigned pack_hi16(unsigned a, unsigned b) {
  return __builtin_amdgcn_perm(a, b, 0x07060302u);
}

// ---------------------------------------------------------------------------
// fp32 -> bf16 bulk convert (8 elements / thread)
// ---------------------------------------------------------------------------
__global__ __launch_bounds__(256) void cvt_bf16(const float* __restrict__ in,
                                                unsigned short* __restrict__ out,
                                                int n8) {
  int i = blockIdx.x * 256 + threadIdx.x;
  if (i >= n8) return;
  const float4v* p = (const float4v*)in;
  float4v a = p[i * 2], b = p[i * 2 + 1];
  uint4v w;
  w[0] = pack_hi16(rne_adj(a[1]), rne_adj(a[0]));
  w[1] = pack_hi16(rne_adj(a[3]), rne_adj(a[2]));
  w[2] = pack_hi16(rne_adj(b[1]), rne_adj(b[0]));
  w[3] = pack_hi16(rne_adj(b[3]), rne_adj(b[2]));
  ((uint4v*)out)[i] = w;
}

// three weight matrices in one launch (288 blocks each)
__global__ __launch_bounds__(256) void cvt_w3(const float* __restrict__ w0,
                                              const float* __restrict__ w1,
                                              const float* __restrict__ w2,
                                              unsigned short* __restrict__ o0,
                                              unsigned short* __restrict__ o1,
                                              unsigned short* __restrict__ o2) {
  int mi = blockIdx.x / 288;
  int i = (blockIdx.x - mi * 288) * 256 + threadIdx.x;
  const float* in = (mi == 0) ? w0 : (mi == 1) ? w1 : w2;
  unsigned short* out = (mi == 0) ? o0 : (mi == 1) ? o1 : o2;
  const float4v* p = (const float4v*)in;
  float4v a = p[i * 2], b = p[i * 2 + 1];
  uint4v w;
  w[0] = pack_hi16(rne_adj(a[1]), rne_adj(a[0]));
  w[1] = pack_hi16(rne_adj(a[3]), rne_adj(a[2]));
  w[2] = pack_hi16(rne_adj(b[1]), rne_adj(b[0]));
  w[3] = pack_hi16(rne_adj(b[3]), rne_adj(b[2]));
  ((uint4v*)out)[i] = w;
}

// ---------------------------------------------------------------------------
// QK-proj GEMM, bare-barrier pipeline: [q|k] = x[8192,768]*Wqk[1536,768]^T.
// 128x128 tile, BK=64, 12 K-iters, 4 waves (2x2 of 64x64), dbuf 64 KB LDS
// -> 2 blocks/CU.  Each wave stages the full fragment set it consumes (wave
// pairs double-write identical bytes), so its OWN vmcnt(16) proves data
// readiness.  Overwrite safety (round-7 bug: skewed partner re-stages bytes
// a wave still reads) comes from ONE bare s_barrier per tile placed after
// loadf+lgkm-drain and before the re-stage — prefetch DMAs for the other
// buffer stay in flight across it (no vmcnt(0) drain anywhere in the loop).
//   per tile: VM_WAIT(16) -> loadf -> lgkm(0) -> s_barrier -> stage(t+2) -> dot
// Grid (64 m, 12 n): m fast => m-tile m lives on XCD m%8; A-slice L2-resident.
// Writes q bf16 (bias + 0.125*log2e folded -> attn uses native exp2),
// k bf16 row-major, kt bf16 [96][64][1024] perm s-order
//   slot(s) = (s&~15) + ((s>>2)&1)*8 + ((s>>3)&1)*4 + (s&3)
// ---------------------------------------------------------------------------
__global__ __launch_bounds__(256, 2) void sgemm_qk(
    const unsigned short* __restrict__ A, const unsigned short* __restrict__ B,
    const float* __restrict__ bias0, const float* __restrict__ bias1,
    unsigned short* __restrict__ outq, unsigned short* __restrict__ outk,
    unsigned short* __restrict__ outkt) {
  __shared__ __align__(16) unsigned short aB[2][8192];  // 2 x 128 rows x 64 k
  __shared__ __align__(16) unsigned short bB[2][8192];
  const int tid = threadIdx.x;
  const int w = tid >> 6, lane = tid & 63;
  const int Q4 = lane >> 4, r = lane & 15;
  const int m0 = blockIdx.x * 128;   // m fast-varying -> XCD-aligned A reuse
  const int n0 = blockIdx.y * 128;
  const int wm = w >> 1, wn = w & 1;

  float4v acc[4][4];
#pragma unroll
  for (int i = 0; i < 4; ++i)
#pragma unroll
    for (int j = 0; j < 4; ++j)
#pragma unroll
      for (int g = 0; g < 4; ++g) acc[i][j][g] = 0.0f;

  // per-wave global bases: this wave's own 64 A-rows / 64 B-rows
  const unsigned short* Abase = A + (size_t)(m0 + wm * 64 + r) * 768 + Q4 * 8;
  const unsigned short* Bbase = B + (size_t)(n0 + wn * 64 + r) * 768 + Q4 * 8;

  // stage the 16 halves THIS wave consumes (j = chunk*2+kh within its 64 rows)
  auto stage = [&](int buf, int kt) {
#pragma unroll
    for (int j = 0; j < 8; ++j)
      async16(&aB[buf][(wm * 8 + j) * 512 + lane * 8],
              Abase + (j >> 1) * (16 * 768) + kt + (j & 1) * 32);
#pragma unroll
    for (int j = 0; j < 8; ++j)
      async16(&bB[buf][(wn * 8 + j) * 512 + lane * 8],
              Bbase + (j >> 1) * (16 * 768) + kt + (j & 1) * 32);
  };

  short8 af[4][2], bf[4][2];
  auto loadf = [&](int buf) {
#pragma unroll
    for (int i = 0; i < 4; ++i)
#pragma unroll
      for (int ks = 0; ks < 2; ++ks) {
        af[i][ks] = *(const short8*)&aB[buf][(wm * 8 + i * 2 + ks) * 512 + lane * 8];
        bf[i][ks] = *(const short8*)&bB[buf][(wn * 8 + i * 2 + ks) * 512 + lane * 8];
      }
  };

  auto dot = [&]() {
#pragma unroll
    for (int mt = 0; mt < 4; ++mt)
#pragma unroll
      for (int nt = 0; nt < 4; ++nt)
#pragma unroll
        for (int ks = 0; ks < 2; ++ks)
          acc[mt][nt] = __builtin_amdgcn_mfma_f32_16x16x32_bf16(
              af[mt][ks], bf[nt][ks], acc[mt][nt], 0, 0, 0);
  };

  stage(0, 0); stage(1, 64);          // tiles 0,1 in flight (32 loads/wave)
#pragma unroll 1
  for (int j = 0; j < 5; ++j) {       // t = 2j, 2j+1  (t = 0..9)
    VM_WAIT(16); loadf(0); LGKM_WAIT; BARRIER; stage(0, j * 128 + 128); dot();
    VM_WAIT(16); loadf(1); LGKM_WAIT; BARRIER; stage(1, j * 128 + 192); dot();
  }
  VM_WAIT(16); loadf(0); dot();       // t = 10 (no re-stage: no barrier needed)
  VM_WAIT(0);  loadf(1); dot();       // t = 11

  // epilogue: C/D layout row = Q4*4+reg, col = r within each 16x16 tile
  const bool isq = (n0 < 768);            // block-uniform (768 % 128 == 0)
  const float* bias = isq ? bias0 : bias1;
  unsigned short* outp = isq ? outq : outk;
  const int nb = isq ? n0 : (n0 - 768);
  // q scale: 1/8 softmax * log2(e) so attention uses native exp2 (exact id)
  const float scl = isq ? 0.18033688011112042f : 1.0f;
#pragma unroll
  for (int nt = 0; nt < 4; ++nt) {
    int n = nb + wn * 64 + nt * 16 + r;
    float bv = bias[n];
#pragma unroll
    for (int mt = 0; mt < 4; ++mt) {
      int m = m0 + wm * 64 + mt * 16 + Q4 * 4;
#pragma unroll
      for (int g = 0; g < 4; ++g)
        outp[(size_t)(m + g) * 768 + n] = (unsigned short)bf16b((acc[mt][nt][g] + bv) * scl);
    }
  }
  if (!isq) {
    // kt permuted write: 4 consecutive perm-slots per (mt,nt) -> one 8B store
    const int bq = m0 >> 10;
    const int sbase = (m0 & 1023) + wm * 64 + (Q4 & 1) * 8 + (Q4 >> 1) * 4;
#pragma unroll
    for (int nt = 0; nt < 4; ++nt) {
      int n = nb + wn * 64 + nt * 16 + r;
      int hh = n >> 6, dd = n & 63;
      float bv = bias[n];
#pragma unroll
      for (int mt = 0; mt < 4; ++mt) {
        int ns = sbase + mt * 16;
        unsigned lo = pack_hi16(rne_adj(acc[mt][nt][1] + bv), rne_adj(acc[mt][nt][0] + bv));
        unsigned hi = pack_hi16(rne_adj(acc[mt][nt][3] + bv), rne_adj(acc[mt][nt][2] + bv));
        *(U2*)(outkt + (size_t)((bq * 12 + hh) * 64 + dd) * 1024 + ns) = U2{lo, hi};
      }
    }
  }
}

// ---------------------------------------------------------------------------
// Out-proj GEMM: out = ao[8192,768] * Wo[768,768]^T + bo (fp32 out).
// 64x128 tile, BK=64 -> 12 iters, grid (6,128) = 768 blocks (3 blocks/CU),
// 4 waves (2x2 of 32x64), 24 KB LDS.  (round-6-proven form)
// ---------------------------------------------------------------------------
__global__ __launch_bounds__(256, 3) void sgemm_out(
    const unsigned short* __restrict__ A, const unsigned short* __restrict__ B,
    const float* __restrict__ bias, float* __restrict__ outp) {
  __shared__ __align__(16) unsigned short a_l[4096];  // 64 rows x 64 k
  __shared__ __align__(16) unsigned short b_l[8192];  // 128 rows x 64 k
  const int tid = threadIdx.x;
  const int w = tid >> 6, lane = tid & 63;
  const int Q4 = lane >> 4, r = lane & 15;
  const int m0 = blockIdx.y * 64;
  const int n0 = blockIdx.x * 128;
  const int wm = w >> 1, wn = w & 1;

  float4v acc[2][4];
#pragma unroll
  for (int i = 0; i < 2; ++i)
#pragma unroll
    for (int j = 0; j < 4; ++j)
#pragma unroll
      for (int g = 0; g < 4; ++g) acc[i][j][g] = 0.0f;

  const unsigned short* Ab = A + (size_t)(m0 + r) * 768 + Q4 * 8;
  const unsigned short* Bb = B + (size_t)(n0 + r) * 768 + Q4 * 8;

  for (int kt = 0; kt < 768; kt += 64) {
    __syncthreads();
#pragma unroll
    for (int ci = 0; ci < 2; ++ci) {      // A: 8 chunk-halves, 2/wave
      int idx = w * 2 + ci;
      int c = idx >> 1, kh = idx & 1;
      async16(&a_l[idx * 512 + lane * 8], Ab + c * 16 * 768 + kt + kh * 32);
    }
#pragma unroll
    for (int ci = 0; ci < 4; ++ci) {      // B: 16 chunk-halves, 4/wave
      int idx = w * 4 + ci;
      int c = idx >> 1, kh = idx & 1;
      async16(&b_l[idx * 512 + lane * 8], Bb + c * 16 * 768 + kt + kh * 32);
    }
    __syncthreads();

    short8 af[2][2], bf[4][2];
#pragma unroll
    for (int i = 0; i < 2; ++i)
#pragma unroll
      for (int ks = 0; ks < 2; ++ks)
        af[i][ks] = *(const short8*)&a_l[((wm * 2 + i) * 2 + ks) * 512 + lane * 8];
#pragma unroll
    for (int i = 0; i < 4; ++i)
#pragma unroll
      for (int ks = 0; ks < 2; ++ks)
        bf[i][ks] = *(const short8*)&b_l[((wn * 4 + i) * 2 + ks) * 512 + lane * 8];
#pragma unroll
    for (int mt = 0; mt < 2; ++mt)
#pragma unroll
      for (int nt = 0; nt < 4; ++nt)
#pragma unroll
        for (int ks = 0; ks < 2; ++ks)
          acc[mt][nt] = __builtin_amdgcn_mfma_f32_16x16x32_bf16(
              af[mt][ks], bf[nt][ks], acc[mt][nt], 0, 0, 0);
  }

#pragma unroll
  for (int nt = 0; nt < 4; ++nt) {
    int n = n0 + wn * 64 + nt * 16 + r;
    float bv = bias[n];
#pragma unroll
    for (int mt = 0; mt < 2; ++mt) {
      int m = m0 + wm * 32 + mt * 16 + Q4 * 4;
#pragma unroll
      for (int g = 0; g < 4; ++g)
        outp[(size_t)(m + g) * 768 + n] = acc[mt][nt][g] + bv;
    }
  }
}

// ---------------------------------------------------------------------------
// Flash attention, v = k, no-max softmax (scores bounded; exactly equivalent;
// q pre-scaled by 0.125*log2e so P = exp2(Sc) natively).
// Block = (b, h, 128 q-rows), 4 waves; wave owns 32 q-cols end-to-end.
// Sc^T = K * Q^T via 32x32x16 MFMA (C: col=q=lane&31, row=s=(reg&3)+8*(reg>>2)+4*hi)
// P = exp2(Sc) via raw v_exp_f32; RNE-pack via v_bfe+v_add3+v_perm (2.5/elem)
// straight into the PV B-fragment (k-order matches C-layout residency via the
// pre-permuted kt array).  O^T = V^T * P^T.  l = deferred single shfl_xor.
// ---------------------------------------------------------------------------
__global__ __launch_bounds__(256, 3) void attn_fused(
    const unsigned short* __restrict__ qg,   // [8192][768], scaled bf16
    const unsigned short* __restrict__ kg,   // [8192][768]
    const unsigned short* __restrict__ ktg,  // [96][64][1024] perm s-order
    unsigned short* __restrict__ ao) {       // [8192][768]
  __shared__ __align__(16) unsigned short q_l[8192];   // 16 KB: 128q x 64d
  __shared__ __align__(16) unsigned short k_l[8192];   // 16 KB: 128s x 64d
  __shared__ __align__(16) unsigned short vt_l[8192];  // 16 KB: 64d x 128s(perm)

  const int tid = threadIdx.x;
  const int w = tid >> 6, lane = tid & 63;
  const int l31 = lane & 31, hi = lane >> 5;
  const int bid = blockIdx.x;
  const int b = bid & 7;                 // XCD-aligned: one batch per XCD
  const int h = bid >> 6;                // 0..11, slow -> L2 working set small
  const int qt = (bid >> 3) & 7;
  const int q0 = qt * 128;
  const int bh = b * 12 + h;

  // stage Q (once) + first K/Vt tiles
#pragma unroll
  for (int ci = 0; ci < 4; ++ci) {
    int c = w * 4 + ci;
    async16(&q_l[c * 512 + lane * 8],
            qg + ((size_t)(b * 1024 + q0 + (c >> 2) * 32 + l31) * 768 + h * 64 + (c & 3) * 16 + hi * 8));
    async16(&k_l[c * 512 + lane * 8],
            kg + ((size_t)(b * 1024 + (c >> 2) * 32 + l31) * 768 + h * 64 + (c & 3) * 16 + hi * 8));
    async16(&vt_l[c * 512 + lane * 8],
            ktg + ((size_t)(bh * 64 + (c >> 3) * 32 + l31) * 1024 + (c & 7) * 16 + hi * 8));
  }
  __syncthreads();

  short8 bfq[4];  // wave's 32 q-cols x 64 d, persistent across all K-tiles
#pragma unroll
  for (int kb = 0; kb < 4; ++kb)
    bfq[kb] = *(const short8*)&q_l[(w * 4 + kb) * 512 + lane * 8];

  float16v o_acc[2];
#pragma unroll
  for (int db = 0; db < 2; ++db)
#pragma unroll
    for (int e = 0; e < 16; ++e) o_acc[db][e] = 0.0f;
  float ps = 0.0f;

#pragma unroll 1
  for (int it = 0; it < 8; ++it) {
    if (it > 0) {
      const int s0 = it * 128;
      __syncthreads();  // prior tile's LDS reads done
#pragma unroll
      for (int ci = 0; ci < 4; ++ci) {
        int c = w * 4 + ci;
        async16(&k_l[c * 512 + lane * 8],
                kg + ((size_t)(b * 1024 + s0 + (c >> 2) * 32 + l31) * 768 + h * 64 + (c & 3) * 16 + hi * 8));
        async16(&vt_l[c * 512 + lane * 8],
                ktg + ((size_t)(bh * 64 + (c >> 3) * 32 + l31) * 1024 + s0 + (c & 7) * 16 + hi * 8));
      }
      __syncthreads();  // staging landed
    }

    // Sc^T = K * Q^T : 128 s x 32 q (this wave), 16 MFMA, 16 ds_read_b128
    float16v sc[4];
#pragma unroll
    for (int sb = 0; sb < 4; ++sb)
#pragma unroll
      for (int e = 0; e < 16; ++e) sc[sb][e] = 0.0f;
#pragma unroll
    for (int sb = 0; sb < 4; ++sb)
#pragma unroll
      for (int kb = 0; kb < 4; ++kb) {
        short8 af = *(const short8*)&k_l[(sb * 4 + kb) * 512 + lane * 8];
        sc[sb] = __builtin_amdgcn_mfma_f32_32x32x16_bf16(af, bfq[kb], sc[sb], 0, 0, 0);
      }

    // P = exp2(Sc) raw v_exp_f32; RNE bf16 pack via v_perm into B-fragments;
    // O^T += V^T * P^T : 16 MFMA, 16 ds_read_b128
#pragma unroll
    for (int sb = 0; sb < 4; ++sb) {
      float pe[16];
#pragma unroll
      for (int e = 0; e < 16; ++e) pe[e] = __builtin_amdgcn_exp2f(sc[sb][e]);
#pragma unroll
      for (int e = 0; e < 16; ++e) ps += pe[e];
      uint4v w0, w1;
#pragma unroll
      for (int p = 0; p < 4; ++p) {
        w0[p] = pack_hi16(rne_adj(pe[2 * p + 1]), rne_adj(pe[2 * p]));
        w1[p] = pack_hi16(rne_adj(pe[2 * p + 9]), rne_adj(pe[2 * p + 8]));
      }
      short8 pf0 = __builtin_bit_cast(short8, w0);
      short8 pf1 = __builtin_bit_cast(short8, w1);
#pragma unroll
      for (int db = 0; db < 2; ++db) {
        short8 vf0 = *(const short8*)&vt_l[(db * 8 + sb * 2) * 512 + lane * 8];
        o_acc[db] = __builtin_amdgcn_mfma_f32_32x32x16_bf16(vf0, pf0, o_acc[db], 0, 0, 0);
        short8 vf1 = *(const short8*)&vt_l[(db * 8 + sb * 2 + 1) * 512 + lane * 8];
        o_acc[db] = __builtin_amdgcn_mfma_f32_32x32x16_bf16(vf1, pf1, o_acc[db], 0, 0, 0);
      }
    }
  }

  // l: hi-halves hold complementary s-rows -> one xor-32 completes the sum
  ps += __shfl_xor(ps, 32, 64);
  const float inv = 1.0f / ps;
  const size_t rowbase = (size_t)(b * 1024 + q0 + w * 32 + l31) * 768 + h * 64;
#pragma unroll
  for (int db = 0; db < 2; ++db)
#pragma unroll
    for (int qq = 0; qq < 4; ++qq) {
      unsigned lo = pack_hi16(rne_adj(o_acc[db][qq * 4 + 1] * inv),
                              rne_adj(o_acc[db][qq * 4 + 0] * inv));
      unsigned hh = pack_hi16(rne_adj(o_acc[db][qq * 4 + 3] * inv),
                              rne_adj(o_acc[db][qq * 4 + 2] * inv));
      *(U2*)(ao + rowbase + db * 32 + qq * 8 + hi * 4) = U2{lo, hh};
    }
}

// ---------------------------------------------------------------------------
extern "C" void kernel_launch(void* const* d_in, const int* in_sizes, int n_in,
                              void* d_out, int out_size, void* d_ws, size_t ws_size,
                              hipStream_t stream) {
  const float* x  = (const float*)d_in[0];
  const float* Wq = (const float*)d_in[1];
  const float* bq = (const float*)d_in[2];
  const float* Wk = (const float*)d_in[3];
  const float* bk = (const float*)d_in[4];
  const float* Wo = (const float*)d_in[5];
  const float* bo = (const float*)d_in[6];
  (void)in_sizes; (void)n_in; (void)out_size; (void)ws_size;

  char* ws = (char*)d_ws;
  unsigned short* x_b   = (unsigned short*)(ws);              // 12,582,912 B
  unsigned short* wqk_b = (unsigned short*)(ws + 12582912);   //  2,359,296 B  [Wq;Wk]
  unsigned short* wo_b  = (unsigned short*)(ws + 14942208);   //  1,179,648 B
  unsigned short* q_b   = (unsigned short*)(ws + 16121856);   // 12,582,912 B
  unsigned short* k_b   = (unsigned short*)(ws + 28704768);   // 12,582,912 B
  unsigned short* kt_b  = (unsigned short*)(ws + 41287680);   // 12,582,912 B
  unsigned short* ao_b  = (unsigned short*)(ws + 53870592);   // 12,582,912 B

  cvt_bf16<<<3072, 256, 0, stream>>>(x, x_b, 786432);
  cvt_w3<<<864, 256, 0, stream>>>(Wq, Wk, Wo, wqk_b, wqk_b + 589824, wo_b);

  // q = (x Wq^T + bq)*0.125*log2e (bf16), k = x Wk^T + bk (row-major + perm kt)
  sgemm_qk<<<dim3(64, 12), 256, 0, stream>>>(x_b, wqk_b, bq, bk, q_b, k_b, kt_b);
  attn_fused<<<768, 256, 0, stream>>>(q_b, k_b, kt_b, ao_b);
  // out = ao Wo^T + bo (fp32)
  sgemm_out<<<dim3(6, 128), 256, 0, stream>>>(ao_b, wo_b, bo, (float*)d_out);
}

// Round 9
// 200.341 us; speedup vs baseline: 1.1606x; 1.1606x over previous
//
#include <hip/hip_runtime.h>
#include <stdint.h>

// ---------------------------------------------------------------------------
// out = softmax((x Wq^T + bq)(x Wk^T + bk)^T / 8) (x Wk^T + bk) Wo^T + bo
// (v = k per the reference's faithful bug)
// B=8 S=1024 E=768 NH=12 D=64.  All GEMMs bf16-MFMA with fp32 accumulate.
// ---------------------------------------------------------------------------

using short8   = __attribute__((ext_vector_type(8))) short;
using uint4v   = __attribute__((ext_vector_type(4))) unsigned;
using float4v  = __attribute__((ext_vector_type(4))) float;
using float16v = __attribute__((ext_vector_type(16))) float;

struct __align__(8) U2 { unsigned x, y; };

__device__ __forceinline__ void async16(void* lds, const void* g) {
  __builtin_amdgcn_global_load_lds(
      (const __attribute__((address_space(1))) void*)g,
      (__attribute__((address_space(3))) void*)lds, 16, 0, 0);
}

#define LGKM_WAIT  asm volatile("s_waitcnt lgkmcnt(0)" ::: "memory")
// bare workgroup barrier WITHOUT the vmcnt(0) drain __syncthreads forces:
// in-flight register prefetch loads cross it untouched.
#define BARRIER    asm volatile("s_barrier" ::: "memory")

// fp32 -> bf16 bits, round-to-nearest-even
__device__ __forceinline__ unsigned bf16b(float f) {
  union { float f; unsigned u; } v; v.f = f;
  unsigned r = v.u + 0x7FFFu + ((v.u >> 16) & 1u);
  return r >> 16;
}
// RNE adjust only (bf16 = high 16 bits of result): 2 VALU
__device__ __forceinline__ unsigned rne_adj(float f) {
  union { float f; unsigned u; } v; v.f = f;
  return v.u + 0x7FFFu + ((v.u >> 16) & 1u);
}
// pack hi16(a):hi16(b) -> one v_perm_b32
__device__ __forceinline__ unsigned pack_hi16(unsigned a, unsigned b) {
  return __builtin_amdgcn_perm(a, b, 0x07060302u);
}

// ---------------------------------------------------------------------------
// fp32 -> bf16 bulk convert (8 elements / thread)
// ---------------------------------------------------------------------------
__global__ __launch_bounds__(256) void cvt_bf16(const float* __restrict__ in,
                                                unsigned short* __restrict__ out,
                                                int n8) {
  int i = blockIdx.x * 256 + threadIdx.x;
  if (i >= n8) return;
  const float4v* p = (const float4v*)in;
  float4v a = p[i * 2], b = p[i * 2 + 1];
  uint4v w;
  w[0] = pack_hi16(rne_adj(a[1]), rne_adj(a[0]));
  w[1] = pack_hi16(rne_adj(a[3]), rne_adj(a[2]));
  w[2] = pack_hi16(rne_adj(b[1]), rne_adj(b[0]));
  w[3] = pack_hi16(rne_adj(b[3]), rne_adj(b[2]));
  ((uint4v*)out)[i] = w;
}

// three weight matrices in one launch (288 blocks each)
__global__ __launch_bounds__(256) void cvt_w3(const float* __restrict__ w0,
                                              const float* __restrict__ w1,
                                              const float* __restrict__ w2,
                                              unsigned short* __restrict__ o0,
                                              unsigned short* __restrict__ o1,
                                              unsigned short* __restrict__ o2) {
  int mi = blockIdx.x / 288;
  int i = (blockIdx.x - mi * 288) * 256 + threadIdx.x;
  const float* in = (mi == 0) ? w0 : (mi == 1) ? w1 : w2;
  unsigned short* out = (mi == 0) ? o0 : (mi == 1) ? o1 : o2;
  const float4v* p = (const float4v*)in;
  float4v a = p[i * 2], b = p[i * 2 + 1];
  uint4v w;
  w[0] = pack_hi16(rne_adj(a[1]), rne_adj(a[0]));
  w[1] = pack_hi16(rne_adj(a[3]), rne_adj(a[2]));
  w[2] = pack_hi16(rne_adj(b[1]), rne_adj(b[0]));
  w[3] = pack_hi16(rne_adj(b[3]), rne_adj(b[2]));
  ((uint4v*)out)[i] = w;
}

// ---------------------------------------------------------------------------
// QK-proj GEMM, register-prefetch pipeline: [q|k] = x[8192,768]*Wqk^T (+bias).
// 128x128 tile, BK=64, 12 K-iters, 4 waves, 32 KB LDS single-buffer
// -> 3 blocks/CU.  Tile t+1 is prefetched into VGPRs by plain global_load
// (compiler-tracked deps; no manual vmcnt), so the ~500-cyc global latency
// hides under dot(t).  Barriers are BARE s_barrier (no vmcnt drain):
//   per tile: [t>0] barrier        (all waves consumed tile t-1: dot's own
//                                   lgkm waits prove their ds_reads retired)
//             ds_write regs->LDS   (compiler waits vmcnt for the loaded regs)
//             global_load t+1      (in flight across everything below)
//             lgkm(0) + barrier    (my writes retired + all waves' visible)
//             ds_read -> dot
// Grid (64 m, 12 n): m fast -> XCD-aligned A-slice L2 reuse (R8: FETCH 53->20MB).
// Writes q bf16 (bias + 0.125*log2e folded -> attn uses native exp2),
// k bf16 row-major, kt bf16 [96][64][1024] perm s-order
//   slot(s) = (s&~15) + ((s>>2)&1)*8 + ((s>>3)&1)*4 + (s&3)
// ---------------------------------------------------------------------------
__global__ __launch_bounds__(256, 3) void sgemm_qk(
    const unsigned short* __restrict__ A, const unsigned short* __restrict__ B,
    const float* __restrict__ bias0, const float* __restrict__ bias1,
    unsigned short* __restrict__ outq, unsigned short* __restrict__ outk,
    unsigned short* __restrict__ outkt) {
  __shared__ __align__(16) unsigned short a_l[8192];  // 128 rows x 64 k
  __shared__ __align__(16) unsigned short b_l[8192];
  const int tid = threadIdx.x;
  const int w = tid >> 6, lane = tid & 63;
  const int Q4 = lane >> 4, r = lane & 15;
  const int m0 = blockIdx.x * 128;   // m fast-varying -> XCD-aligned A reuse
  const int n0 = blockIdx.y * 128;
  const int wm = w >> 1, wn = w & 1;

  float4v acc[4][4];
#pragma unroll
  for (int i = 0; i < 4; ++i)
#pragma unroll
    for (int j = 0; j < 4; ++j)
#pragma unroll
      for (int g = 0; g < 4; ++g) acc[i][j][g] = 0.0f;

  const unsigned short* Ab = A + (size_t)(m0 + r) * 768 + Q4 * 8;
  const unsigned short* Bb = B + (size_t)(n0 + r) * 768 + Q4 * 8;

  // register prefetch: this wave's 4 A + 4 B chunk-halves (idx = w*4+ci)
  uint4v ra[4], rb[4];
  auto gload = [&](int kt) {
#pragma unroll
    for (int ci = 0; ci < 4; ++ci) {
      int idx = w * 4 + ci, c = idx >> 1, kh = idx & 1;
      ra[ci] = *(const uint4v*)(Ab + c * 12288 + kt + kh * 32);
      rb[ci] = *(const uint4v*)(Bb + c * 12288 + kt + kh * 32);
    }
  };
  auto swrite = [&]() {
#pragma unroll
    for (int ci = 0; ci < 4; ++ci) {
      int idx = w * 4 + ci;
      *(uint4v*)&a_l[idx * 512 + lane * 8] = ra[ci];
      *(uint4v*)&b_l[idx * 512 + lane * 8] = rb[ci];
    }
  };

  short8 af[4][2], bf[4][2];
  auto loadf = [&]() {
#pragma unroll
    for (int i = 0; i < 4; ++i)
#pragma unroll
      for (int ks = 0; ks < 2; ++ks) {
        af[i][ks] = *(const short8*)&a_l[((wm * 4 + i) * 2 + ks) * 512 + lane * 8];
        bf[i][ks] = *(const short8*)&b_l[((wn * 4 + i) * 2 + ks) * 512 + lane * 8];
      }
  };
  auto dot = [&]() {
#pragma unroll
    for (int mt = 0; mt < 4; ++mt)
#pragma unroll
      for (int nt = 0; nt < 4; ++nt)
#pragma unroll
        for (int ks = 0; ks < 2; ++ks)
          acc[mt][nt] = __builtin_amdgcn_mfma_f32_16x16x32_bf16(
              af[mt][ks], bf[nt][ks], acc[mt][nt], 0, 0, 0);
  };

  gload(0);
#pragma unroll 1
  for (int t = 0; t < 12; ++t) {
    if (t > 0) BARRIER;              // all waves consumed tile t-1
    swrite();                        // vmcnt waits auto-inserted for ra/rb
    if (t < 11) gload(t * 64 + 64);  // prefetch under this tile's MFMAs
    LGKM_WAIT;                       // my ds_writes retired
    BARRIER;                         // all writes visible; prefetch in flight
    loadf();
    dot();
  }

  // epilogue: C/D layout row = Q4*4+reg, col = r within each 16x16 tile
  const bool isq = (n0 < 768);            // block-uniform (768 % 128 == 0)
  const float* bias = isq ? bias0 : bias1;
  unsigned short* outp = isq ? outq : outk;
  const int nb = isq ? n0 : (n0 - 768);
  // q scale: 1/8 softmax * log2(e) so attention uses native exp2 (exact id)
  const float scl = isq ? 0.18033688011112042f : 1.0f;
#pragma unroll
  for (int nt = 0; nt < 4; ++nt) {
    int n = nb + wn * 64 + nt * 16 + r;
    float bv = bias[n];
#pragma unroll
    for (int mt = 0; mt < 4; ++mt) {
      int m = m0 + wm * 64 + mt * 16 + Q4 * 4;
#pragma unroll
      for (int g = 0; g < 4; ++g)
        outp[(size_t)(m + g) * 768 + n] = (unsigned short)bf16b((acc[mt][nt][g] + bv) * scl);
    }
  }
  if (!isq) {
    // kt permuted write: 4 consecutive perm-slots per (mt,nt) -> one 8B store
    const int bq = m0 >> 10;
    const int sbase = (m0 & 1023) + wm * 64 + (Q4 & 1) * 8 + (Q4 >> 1) * 4;
#pragma unroll
    for (int nt = 0; nt < 4; ++nt) {
      int n = nb + wn * 64 + nt * 16 + r;
      int hh = n >> 6, dd = n & 63;
      float bv = bias[n];
#pragma unroll
      for (int mt = 0; mt < 4; ++mt) {
        int ns = sbase + mt * 16;
        unsigned lo = pack_hi16(rne_adj(acc[mt][nt][1] + bv), rne_adj(acc[mt][nt][0] + bv));
        unsigned hi = pack_hi16(rne_adj(acc[mt][nt][3] + bv), rne_adj(acc[mt][nt][2] + bv));
        *(U2*)(outkt + (size_t)((bq * 12 + hh) * 64 + dd) * 1024 + ns) = U2{lo, hi};
      }
    }
  }
}

// ---------------------------------------------------------------------------
// Out-proj GEMM, same register-prefetch pipeline: out = ao*Wo^T + bo (fp32).
// 64x128 tile, BK=64, 12 iters, grid (6,128) = 768 blocks, 4 waves, 24 KB LDS.
// ---------------------------------------------------------------------------
__global__ __launch_bounds__(256, 3) void sgemm_out(
    const unsigned short* __restrict__ A, const unsigned short* __restrict__ B,
    const float* __restrict__ bias, float* __restrict__ outp) {
  __shared__ __align__(16) unsigned short a_l[4096];  // 64 rows x 64 k
  __shared__ __align__(16) unsigned short b_l[8192];  // 128 rows x 64 k
  const int tid = threadIdx.x;
  const int w = tid >> 6, lane = tid & 63;
  const int Q4 = lane >> 4, r = lane & 15;
  const int m0 = blockIdx.y * 64;
  const int n0 = blockIdx.x * 128;
  const int wm = w >> 1, wn = w & 1;

  float4v acc[2][4];
#pragma unroll
  for (int i = 0; i < 2; ++i)
#pragma unroll
    for (int j = 0; j < 4; ++j)
#pragma unroll
      for (int g = 0; g < 4; ++g) acc[i][j][g] = 0.0f;

  const unsigned short* Ab = A + (size_t)(m0 + r) * 768 + Q4 * 8;
  const unsigned short* Bb = B + (size_t)(n0 + r) * 768 + Q4 * 8;

  uint4v ra[2], rb[4];
  auto gload = [&](int kt) {
#pragma unroll
    for (int ci = 0; ci < 2; ++ci) {
      int idx = w * 2 + ci;
      ra[ci] = *(const uint4v*)(Ab + (idx >> 1) * 12288 + kt + (idx & 1) * 32);
    }
#pragma unroll
    for (int ci = 0; ci < 4; ++ci) {
      int idx = w * 4 + ci;
      rb[ci] = *(const uint4v*)(Bb + (idx >> 1) * 12288 + kt + (idx & 1) * 32);
    }
  };
  auto swrite = [&]() {
#pragma unroll
    for (int ci = 0; ci < 2; ++ci) {
      int idx = w * 2 + ci;
      *(uint4v*)&a_l[idx * 512 + lane * 8] = ra[ci];
    }
#pragma unroll
    for (int ci = 0; ci < 4; ++ci) {
      int idx = w * 4 + ci;
      *(uint4v*)&b_l[idx * 512 + lane * 8] = rb[ci];
    }
  };

  short8 af[2][2], bf[4][2];
  auto loadf = [&]() {
#pragma unroll
    for (int i = 0; i < 2; ++i)
#pragma unroll
      for (int ks = 0; ks < 2; ++ks)
        af[i][ks] = *(const short8*)&a_l[((wm * 2 + i) * 2 + ks) * 512 + lane * 8];
#pragma unroll
    for (int i = 0; i < 4; ++i)
#pragma unroll
      for (int ks = 0; ks < 2; ++ks)
        bf[i][ks] = *(const short8*)&b_l[((wn * 4 + i) * 2 + ks) * 512 + lane * 8];
  };
  auto dot = [&]() {
#pragma unroll
    for (int mt = 0; mt < 2; ++mt)
#pragma unroll
      for (int nt = 0; nt < 4; ++nt)
#pragma unroll
        for (int ks = 0; ks < 2; ++ks)
          acc[mt][nt] = __builtin_amdgcn_mfma_f32_16x16x32_bf16(
              af[mt][ks], bf[nt][ks], acc[mt][nt], 0, 0, 0);
  };

  gload(0);
#pragma unroll 1
  for (int t = 0; t < 12; ++t) {
    if (t > 0) BARRIER;
    swrite();
    if (t < 11) gload(t * 64 + 64);
    LGKM_WAIT;
    BARRIER;
    loadf();
    dot();
  }

#pragma unroll
  for (int nt = 0; nt < 4; ++nt) {
    int n = n0 + wn * 64 + nt * 16 + r;
    float bv = bias[n];
#pragma unroll
    for (int mt = 0; mt < 2; ++mt) {
      int m = m0 + wm * 32 + mt * 16 + Q4 * 4;
#pragma unroll
      for (int g = 0; g < 4; ++g)
        outp[(size_t)(m + g) * 768 + n] = acc[mt][nt][g] + bv;
    }
  }
}

// ---------------------------------------------------------------------------
// Flash attention, v = k, no-max softmax (scores bounded; exactly equivalent;
// q pre-scaled by 0.125*log2e so P = exp2(Sc) natively).  (round-6-proven)
// Block = (b, h, 128 q-rows), 4 waves; wave owns 32 q-cols end-to-end.
// Sc^T = K * Q^T via 32x32x16 MFMA (C: col=q=lane&31, row=s=(reg&3)+8*(reg>>2)+4*hi)
// P = exp2(Sc) via raw v_exp_f32; RNE-pack via v_bfe+v_add3+v_perm (2.5/elem)
// straight into the PV B-fragment (k-order matches C-layout residency via the
// pre-permuted kt array).  O^T = V^T * P^T.  l = deferred single shfl_xor.
// ---------------------------------------------------------------------------
__global__ __launch_bounds__(256, 3) void attn_fused(
    const unsigned short* __restrict__ qg,   // [8192][768], scaled bf16
    const unsigned short* __restrict__ kg,   // [8192][768]
    const unsigned short* __restrict__ ktg,  // [96][64][1024] perm s-order
    unsigned short* __restrict__ ao) {       // [8192][768]
  __shared__ __align__(16) unsigned short q_l[8192];   // 16 KB: 128q x 64d
  __shared__ __align__(16) unsigned short k_l[8192];   // 16 KB: 128s x 64d
  __shared__ __align__(16) unsigned short vt_l[8192];  // 16 KB: 64d x 128s(perm)

  const int tid = threadIdx.x;
  const int w = tid >> 6, lane = tid & 63;
  const int l31 = lane & 31, hi = lane >> 5;
  const int bid = blockIdx.x;
  const int b = bid & 7;                 // XCD-aligned: one batch per XCD
  const int h = bid >> 6;                // 0..11, slow -> L2 working set small
  const int qt = (bid >> 3) & 7;
  const int q0 = qt * 128;
  const int bh = b * 12 + h;

  // stage Q (once) + first K/Vt tiles
#pragma unroll
  for (int ci = 0; ci < 4; ++ci) {
    int c = w * 4 + ci;
    async16(&q_l[c * 512 + lane * 8],
            qg + ((size_t)(b * 1024 + q0 + (c >> 2) * 32 + l31) * 768 + h * 64 + (c & 3) * 16 + hi * 8));
    async16(&k_l[c * 512 + lane * 8],
            kg + ((size_t)(b * 1024 + (c >> 2) * 32 + l31) * 768 + h * 64 + (c & 3) * 16 + hi * 8));
    async16(&vt_l[c * 512 + lane * 8],
            ktg + ((size_t)(bh * 64 + (c >> 3) * 32 + l31) * 1024 + (c & 7) * 16 + hi * 8));
  }
  __syncthreads();

  short8 bfq[4];  // wave's 32 q-cols x 64 d, persistent across all K-tiles
#pragma unroll
  for (int kb = 0; kb < 4; ++kb)
    bfq[kb] = *(const short8*)&q_l[(w * 4 + kb) * 512 + lane * 8];

  float16v o_acc[2];
#pragma unroll
  for (int db = 0; db < 2; ++db)
#pragma unroll
    for (int e = 0; e < 16; ++e) o_acc[db][e] = 0.0f;
  float ps = 0.0f;

#pragma unroll 1
  for (int it = 0; it < 8; ++it) {
    if (it > 0) {
      const int s0 = it * 128;
      __syncthreads();  // prior tile's LDS reads done
#pragma unroll
      for (int ci = 0; ci < 4; ++ci) {
        int c = w * 4 + ci;
        async16(&k_l[c * 512 + lane * 8],
                kg + ((size_t)(b * 1024 + s0 + (c >> 2) * 32 + l31) * 768 + h * 64 + (c & 3) * 16 + hi * 8));
        async16(&vt_l[c * 512 + lane * 8],
                ktg + ((size_t)(bh * 64 + (c >> 3) * 32 + l31) * 1024 + s0 + (c & 7) * 16 + hi * 8));
      }
      __syncthreads();  // staging landed
    }

    // Sc^T = K * Q^T : 128 s x 32 q (this wave), 16 MFMA, 16 ds_read_b128
    float16v sc[4];
#pragma unroll
    for (int sb = 0; sb < 4; ++sb)
#pragma unroll
      for (int e = 0; e < 16; ++e) sc[sb][e] = 0.0f;
#pragma unroll
    for (int sb = 0; sb < 4; ++sb)
#pragma unroll
      for (int kb = 0; kb < 4; ++kb) {
        short8 af = *(const short8*)&k_l[(sb * 4 + kb) * 512 + lane * 8];
        sc[sb] = __builtin_amdgcn_mfma_f32_32x32x16_bf16(af, bfq[kb], sc[sb], 0, 0, 0);
      }

    // P = exp2(Sc) raw v_exp_f32; RNE bf16 pack via v_perm into B-fragments;
    // O^T += V^T * P^T : 16 MFMA, 16 ds_read_b128
#pragma unroll
    for (int sb = 0; sb < 4; ++sb) {
      float pe[16];
#pragma unroll
      for (int e = 0; e < 16; ++e) pe[e] = __builtin_amdgcn_exp2f(sc[sb][e]);
#pragma unroll
      for (int e = 0; e < 16; ++e) ps += pe[e];
      uint4v w0, w1;
#pragma unroll
      for (int p = 0; p < 4; ++p) {
        w0[p] = pack_hi16(rne_adj(pe[2 * p + 1]), rne_adj(pe[2 * p]));
        w1[p] = pack_hi16(rne_adj(pe[2 * p + 9]), rne_adj(pe[2 * p + 8]));
      }
      short8 pf0 = __builtin_bit_cast(short8, w0);
      short8 pf1 = __builtin_bit_cast(short8, w1);
#pragma unroll
      for (int db = 0; db < 2; ++db) {
        short8 vf0 = *(const short8*)&vt_l[(db * 8 + sb * 2) * 512 + lane * 8];
        o_acc[db] = __builtin_amdgcn_mfma_f32_32x32x16_bf16(vf0, pf0, o_acc[db], 0, 0, 0);
        short8 vf1 = *(const short8*)&vt_l[(db * 8 + sb * 2 + 1) * 512 + lane * 8];
        o_acc[db] = __builtin_amdgcn_mfma_f32_32x32x16_bf16(vf1, pf1, o_acc[db], 0, 0, 0);
      }
    }
  }

  // l: hi-halves hold complementary s-rows -> one xor-32 completes the sum
  ps += __shfl_xor(ps, 32, 64);
  const float inv = 1.0f / ps;
  const size_t rowbase = (size_t)(b * 1024 + q0 + w * 32 + l31) * 768 + h * 64;
#pragma unroll
  for (int db = 0; db < 2; ++db)
#pragma unroll
    for (int qq = 0; qq < 4; ++qq) {
      unsigned lo = pack_hi16(rne_adj(o_acc[db][qq * 4 + 1] * inv),
                              rne_adj(o_acc[db][qq * 4 + 0] * inv));
      unsigned hh = pack_hi16(rne_adj(o_acc[db][qq * 4 + 3] * inv),
                              rne_adj(o_acc[db][qq * 4 + 2] * inv));
      *(U2*)(ao + rowbase + db * 32 + qq * 8 + hi * 4) = U2{lo, hh};
    }
}

// ---------------------------------------------------------------------------
extern "C" void kernel_launch(void* const* d_in, const int* in_sizes, int n_in,
                              void* d_out, int out_size, void* d_ws, size_t ws_size,
                              hipStream_t stream) {
  const float* x  = (const float*)d_in[0];
  const float* Wq = (const float*)d_in[1];
  const float* bq = (const float*)d_in[2];
  const float* Wk = (const float*)d_in[3];
  const float* bk = (const float*)d_in[4];
  const float* Wo = (const float*)d_in[5];
  const float* bo = (const float*)d_in[6];
  (void)in_sizes; (void)n_in; (void)out_size; (void)ws_size;

  char* ws = (char*)d_ws;
  unsigned short* x_b   = (unsigned short*)(ws);              // 12,582,912 B
  unsigned short* wqk_b = (unsigned short*)(ws + 12582912);   //  2,359,296 B  [Wq;Wk]
  unsigned short* wo_b  = (unsigned short*)(ws + 14942208);   //  1,179,648 B
  unsigned short* q_b   = (unsigned short*)(ws + 16121856);   // 12,582,912 B
  unsigned short* k_b   = (unsigned short*)(ws + 28704768);   // 12,582,912 B
  unsigned short* kt_b  = (unsigned short*)(ws + 41287680);   // 12,582,912 B
  unsigned short* ao_b  = (unsigned short*)(ws + 53870592);   // 12,582,912 B

  cvt_bf16<<<3072, 256, 0, stream>>>(x, x_b, 786432);
  cvt_w3<<<864, 256, 0, stream>>>(Wq, Wk, Wo, wqk_b, wqk_b + 589824, wo_b);

  // q = (x Wq^T + bq)*0.125*log2e (bf16), k = x Wk^T + bk (row-major + perm kt)
  sgemm_qk<<<dim3(64, 12), 256, 0, stream>>>(x_b, wqk_b, bq, bk, q_b, k_b, kt_b);
  attn_fused<<<768, 256, 0, stream>>>(q_b, k_b, kt_b, ao_b);
  // out = ao Wo^T + bo (fp32)
  sgemm_out<<<dim3(6, 128), 256, 0, stream>>>(ao_b, wo_b, bo, (float*)d_out);
}